// Round 7
// baseline (3701.220 us; speedup 1.0000x reference)
//
#include <hip/hip_runtime.h>

#define Q_INV (1.0f / 128.0f)

__device__ __forceinline__ float quant_comp_f(float v) {
    float f = floorf(v * 128.0f);
    f = fminf(fmaxf(f, -128.0f), 127.0f);
    int qi = (int)f;
    qi |= 1;
    return (float)qi * Q_INV;
}

// One block per image, 192 threads. Chains bit-identical to R4 (verified):
// conv1 (ky,kx) asc incl. zero-pad terms; conv2 (ky,kx,ic) asc; bias as
// separate rounded add; pool fmax trees identical. Vertical pooling via
// shfl_xor(1) — no LDS staging. VGPR capped for 4 waves/SIMD.
__global__ __launch_bounds__(192, 4) void conv_fused_kernel(
    const float* __restrict__ x,
    const float* __restrict__ c1w, const float* __restrict__ c1b,
    const float* __restrict__ c2w, const float* __restrict__ c2b,
    const int* __restrict__ qflag,
    float* __restrict__ act)
{
    __shared__ __align__(16) float pin[32][36];   // stride 36: ~4-way max on row reads
    __shared__ float w1s[150];
    __shared__ float b1s[6];
    __shared__ float w2s[2400];
    __shared__ float b2s[16];
    __shared__ __align__(16) float mid[6][14][20]; // stride 20: collisions only at dRow=8

    const int t = threadIdx.x;
    const int img = blockIdx.x;
    const bool q = (qflag[0] != 0);

    for (int i = t; i < 32 * 36; i += 192) (&pin[0][0])[i] = 0.0f;
    if (t < 150) w1s[t] = c1w[t];
    if (t < 6) b1s[t] = c1b[t];
    for (int i = t; i < 2400; i += 192) w2s[i] = c2w[i];
    if (t < 16) b2s[t] = c2b[t];
    __syncthreads();

    const float* xi = x + (size_t)img * 784;
    for (int i = t; i < 784; i += 192) {
        float v = xi[i];
        if (q) v = quant_comp_f(v);
        pin[i / 28 + 2][i % 28 + 2] = v;
    }
    __syncthreads();

    // ---- conv1: t<168, thread=(c, conv-row oh), 28 outputs in registers ----
    if (t < 168) {
        const int c = t / 28, oh = t % 28;
        float wr[25];
        #pragma unroll
        for (int k = 0; k < 25; ++k) wr[k] = w1s[c * 25 + k];
        float acc[28];
        #pragma unroll
        for (int j = 0; j < 28; ++j) acc[j] = 0.0f;
        #pragma unroll
        for (int ky = 0; ky < 5; ++ky) {
            const float4* pr = reinterpret_cast<const float4*>(&pin[oh + ky][0]);
            float rbf[36];
            #pragma unroll
            for (int j = 0; j < 9; ++j) {
                float4 v4 = pr[j];
                rbf[4*j] = v4.x; rbf[4*j+1] = v4.y;
                rbf[4*j+2] = v4.z; rbf[4*j+3] = v4.w;
            }
            #pragma unroll
            for (int kx = 0; kx < 5; ++kx) {
                const float wv = wr[ky * 5 + kx];
                #pragma unroll
                for (int ow = 0; ow < 28; ++ow)
                    acc[ow] = fmaf(rbf[ow + kx], wv, acc[ow]);
            }
        }
        const float bb = b1s[c];
        float hmax[14];
        #pragma unroll
        for (int j = 0; j < 14; ++j) {
            float v0 = acc[2*j] + bb;       // separate rounded add (as R4)
            float v1 = acc[2*j + 1] + bb;
            hmax[j] = fmaxf(v0, v1);
        }
        // vertical pool: partner lane t^1 holds row oh^1 of same c (pairs never
        // cross a wave boundary: pairs are (2k,2k+1); t parity == oh parity)
        #pragma unroll
        for (int j = 0; j < 14; ++j) {
            float other = __shfl_xor(hmax[j], 1);
            if ((oh & 1) == 0) {
                float m = fmaxf(fmaxf(hmax[j], other), 0.0f);
                if (q) m = quant_comp_f(m);
                mid[c][oh >> 1][j] = m;
            }
        }
    }
    __syncthreads();

    // ---- conv2: t<160, thread=(c, conv-row oh), 10 outputs in registers ----
    if (t < 160) {
        const int c = t / 10, oh = t % 10;
        float acc[10];
        #pragma unroll
        for (int j = 0; j < 10; ++j) acc[j] = 0.0f;
        #pragma unroll
        for (int ky = 0; ky < 5; ++ky) {
            float rf[6][14];
            #pragma unroll
            for (int ic = 0; ic < 6; ++ic) {
                const float* mrow = &mid[ic][oh + ky][0];
                const float4* m4 = reinterpret_cast<const float4*>(mrow);
                #pragma unroll
                for (int j = 0; j < 3; ++j) {
                    float4 v4 = m4[j];
                    rf[ic][4*j] = v4.x; rf[ic][4*j+1] = v4.y;
                    rf[ic][4*j+2] = v4.z; rf[ic][4*j+3] = v4.w;
                }
                const float2 v2 = *reinterpret_cast<const float2*>(mrow + 12);
                rf[ic][12] = v2.x; rf[ic][13] = v2.y;
            }
            #pragma unroll
            for (int kx = 0; kx < 5; ++kx) {
                #pragma unroll
                for (int ic = 0; ic < 6; ++ic) {
                    const float wv = w2s[(c * 6 + ic) * 25 + ky * 5 + kx];
                    #pragma unroll
                    for (int ow = 0; ow < 10; ++ow)
                        acc[ow] = fmaf(rf[ic][ow + kx], wv, acc[ow]);
                }
            }
        }
        const float bb = b2s[c];
        float hmax[5];
        #pragma unroll
        for (int j = 0; j < 5; ++j) {
            float v0 = acc[2*j] + bb;
            float v1 = acc[2*j + 1] + bb;
            hmax[j] = fmaxf(v0, v1);
        }
        float* ao = act + (size_t)img * 400;
        #pragma unroll
        for (int j = 0; j < 5; ++j) {
            float other = __shfl_xor(hmax[j], 1);
            if ((oh & 1) == 0) {
                float m = fmaxf(fmaxf(hmax[j], other), 0.0f);
                if (q) m = quant_comp_f(m);
                ao[c * 25 + (oh >> 1) * 5 + j] = m;
            }
        }
    }
}

// R4 fc kernel verbatim (known-good, 75 µs).
__global__ __launch_bounds__(256) void fc_fused_kernel(
    const float* __restrict__ act,
    const float* __restrict__ w1, const float* __restrict__ b1,
    const float* __restrict__ w2, const float* __restrict__ b2,
    const float* __restrict__ w3, const float* __restrict__ b3,
    const int* __restrict__ qflag,
    float* __restrict__ out, int B)
{
    __shared__ __align__(16) float a0[16][404];
    __shared__ __align__(16) float a1[16][124];
    __shared__ __align__(16) float a2[16][88];

    const int t = threadIdx.x;
    const bool q = (qflag[0] != 0);
    const int base = blockIdx.x * 16;

    for (int i = t; i < 16 * 400; i += 256) {
        const int im = i / 400, k = i % 400;
        if (base + im < B) a0[im][k] = act[(size_t)(base + im) * 400 + k];
    }
    __syncthreads();

    const int im = t & 15;
    const int grp = t >> 4;

    for (int o = grp; o < 120; o += 16) {
        const float4* wr = reinterpret_cast<const float4*>(w1 + o * 400);
        const float4* ar = reinterpret_cast<const float4*>(&a0[im][0]);
        float acc = 0.0f;
        #pragma unroll 4
        for (int kk = 0; kk < 100; ++kk) {
            const float4 av = ar[kk];
            const float4 wv = wr[kk];
            acc = fmaf(av.x, wv.x, acc);
            acc = fmaf(av.y, wv.y, acc);
            acc = fmaf(av.z, wv.z, acc);
            acc = fmaf(av.w, wv.w, acc);
        }
        float v = acc + b1[o];
        v = fmaxf(v, 0.0f);
        a1[im][o] = q ? quant_comp_f(v) : v;
    }
    __syncthreads();

    for (int o = grp; o < 84; o += 16) {
        const float4* wr = reinterpret_cast<const float4*>(w2 + o * 120);
        const float4* ar = reinterpret_cast<const float4*>(&a1[im][0]);
        float acc = 0.0f;
        #pragma unroll 4
        for (int kk = 0; kk < 30; ++kk) {
            const float4 av = ar[kk];
            const float4 wv = wr[kk];
            acc = fmaf(av.x, wv.x, acc);
            acc = fmaf(av.y, wv.y, acc);
            acc = fmaf(av.z, wv.z, acc);
            acc = fmaf(av.w, wv.w, acc);
        }
        float v = acc + b2[o];
        v = fmaxf(v, 0.0f);
        a2[im][o] = q ? quant_comp_f(v) : v;
    }
    __syncthreads();

    for (int o = grp; o < 10; o += 16) {
        const float4* wr = reinterpret_cast<const float4*>(w3 + o * 84);
        const float4* ar = reinterpret_cast<const float4*>(&a2[im][0]);
        float acc = 0.0f;
        #pragma unroll
        for (int kk = 0; kk < 21; ++kk) {
            const float4 av = ar[kk];
            const float4 wv = wr[kk];
            acc = fmaf(av.x, wv.x, acc);
            acc = fmaf(av.y, wv.y, acc);
            acc = fmaf(av.z, wv.z, acc);
            acc = fmaf(av.w, wv.w, acc);
        }
        if (base + im < B) out[(size_t)(base + im) * 10 + o] = acc + b3[o];
    }
}

extern "C" void kernel_launch(void* const* d_in, const int* in_sizes, int n_in,
                              void* d_out, int out_size, void* d_ws, size_t ws_size,
                              hipStream_t stream) {
    const float* x     = (const float*)d_in[0];
    const float* c1w   = (const float*)d_in[1];
    const float* c1b   = (const float*)d_in[2];
    const float* c2w   = (const float*)d_in[3];
    const float* c2b   = (const float*)d_in[4];
    const float* fc1w  = (const float*)d_in[5];
    const float* fc1b  = (const float*)d_in[6];
    const float* fc2w  = (const float*)d_in[7];
    const float* fc2b  = (const float*)d_in[8];
    const float* fc3w  = (const float*)d_in[9];
    const float* fc3b  = (const float*)d_in[10];
    const int*   qflag = (const int*)d_in[11];
    float* out = (float*)d_out;

    const int B = in_sizes[0] / 784;
    float* act = (float*)d_ws;  // [B,400]

    conv_fused_kernel<<<B, 192, 0, stream>>>(x, c1w, c1b, c2w, c2b, qflag, act);

    const int nblk = (B + 15) / 16;
    fc_fused_kernel<<<nblk, 256, 0, stream>>>(act, fc1w, fc1b, fc2w, fc2b,
                                              fc3w, fc3b, qflag, out, B);
}

// Round 8
// 1010.136 us; speedup vs baseline: 3.6641x; 3.6641x over previous
//
#include <hip/hip_runtime.h>

#define Q_INV (1.0f / 128.0f)

__device__ __forceinline__ float quant_comp_f(float v) {
    float f = floorf(v * 128.0f);
    f = fminf(fmaxf(f, -128.0f), 127.0f);
    int qi = (int)f;
    qi |= 1;
    return (float)qi * Q_INV;
}

// One block per image, 192 threads. Chains bit-identical to R4 (verified):
// conv1 (ky,kx) asc incl. zero-pad terms; conv2 (ky,kx,ic) asc; bias as
// separate rounded add; pool fmax trees identical. Vertical pooling via
// shfl_xor(1). NO min-waves launch bound: R7's (192,4) capped VGPR at 64 and
// spilled 13 GB to scratch. Compiler-chosen VGPR (~100) is the right point.
__global__ __launch_bounds__(192) void conv_fused_kernel(
    const float* __restrict__ x,
    const float* __restrict__ c1w, const float* __restrict__ c1b,
    const float* __restrict__ c2w, const float* __restrict__ c2b,
    const int* __restrict__ qflag,
    float* __restrict__ act)
{
    __shared__ __align__(16) float pin[32][36];   // stride 36 (144B): 16B-aligned rows
    __shared__ float w1s[150];
    __shared__ float b1s[6];
    __shared__ float w2s[2400];
    __shared__ float b2s[16];
    __shared__ __align__(16) float mid[6][14][20]; // stride 20: collisions only at dRow=8

    const int t = threadIdx.x;
    const int img = blockIdx.x;
    const bool q = (qflag[0] != 0);

    for (int i = t; i < 32 * 36; i += 192) (&pin[0][0])[i] = 0.0f;
    if (t < 150) w1s[t] = c1w[t];
    if (t < 6) b1s[t] = c1b[t];
    for (int i = t; i < 2400; i += 192) w2s[i] = c2w[i];
    if (t < 16) b2s[t] = c2b[t];
    __syncthreads();

    const float* xi = x + (size_t)img * 784;
    for (int i = t; i < 784; i += 192) {
        float v = xi[i];
        if (q) v = quant_comp_f(v);
        pin[i / 28 + 2][i % 28 + 2] = v;
    }
    __syncthreads();

    // ---- conv1: t<168, thread=(c, conv-row oh), 28 outputs in registers ----
    if (t < 168) {
        const int c = t / 28, oh = t % 28;
        float wr[25];
        #pragma unroll
        for (int k = 0; k < 25; ++k) wr[k] = w1s[c * 25 + k];
        float acc[28];
        #pragma unroll
        for (int j = 0; j < 28; ++j) acc[j] = 0.0f;
        #pragma unroll
        for (int ky = 0; ky < 5; ++ky) {
            const float4* pr = reinterpret_cast<const float4*>(&pin[oh + ky][0]);
            float rbf[32];                       // cols 0..31 (max used: 27+4)
            #pragma unroll
            for (int j = 0; j < 8; ++j) {
                float4 v4 = pr[j];
                rbf[4*j] = v4.x; rbf[4*j+1] = v4.y;
                rbf[4*j+2] = v4.z; rbf[4*j+3] = v4.w;
            }
            #pragma unroll
            for (int kx = 0; kx < 5; ++kx) {
                const float wv = wr[ky * 5 + kx];
                #pragma unroll
                for (int ow = 0; ow < 28; ++ow)
                    acc[ow] = fmaf(rbf[ow + kx], wv, acc[ow]);
            }
        }
        const float bb = b1s[c];
        float hmax[14];
        #pragma unroll
        for (int j = 0; j < 14; ++j) {
            float v0 = acc[2*j] + bb;       // separate rounded add (as R4)
            float v1 = acc[2*j + 1] + bb;
            hmax[j] = fmaxf(v0, v1);
        }
        // vertical pool: partner lane t^1 holds row oh^1 of same c (pairs
        // (2k,2k+1) never straddle a wave boundary; 168 is even)
        #pragma unroll
        for (int j = 0; j < 14; ++j) {
            float other = __shfl_xor(hmax[j], 1);
            if ((oh & 1) == 0) {
                float m = fmaxf(fmaxf(hmax[j], other), 0.0f);
                if (q) m = quant_comp_f(m);
                mid[c][oh >> 1][j] = m;
            }
        }
    }
    __syncthreads();

    // ---- conv2: t<160, thread=(c, conv-row oh), 10 outputs in registers ----
    if (t < 160) {
        const int c = t / 10, oh = t % 10;
        float acc[10];
        #pragma unroll
        for (int j = 0; j < 10; ++j) acc[j] = 0.0f;
        #pragma unroll
        for (int ky = 0; ky < 5; ++ky) {
            float rf[6][14];
            #pragma unroll
            for (int ic = 0; ic < 6; ++ic) {
                const float* mrow = &mid[ic][oh + ky][0];
                const float4* m4 = reinterpret_cast<const float4*>(mrow);
                #pragma unroll
                for (int j = 0; j < 3; ++j) {
                    float4 v4 = m4[j];
                    rf[ic][4*j] = v4.x; rf[ic][4*j+1] = v4.y;
                    rf[ic][4*j+2] = v4.z; rf[ic][4*j+3] = v4.w;
                }
                const float2 v2 = *reinterpret_cast<const float2*>(mrow + 12);
                rf[ic][12] = v2.x; rf[ic][13] = v2.y;
            }
            #pragma unroll
            for (int kx = 0; kx < 5; ++kx) {
                #pragma unroll
                for (int ic = 0; ic < 6; ++ic) {
                    const float wv = w2s[(c * 6 + ic) * 25 + ky * 5 + kx];
                    #pragma unroll
                    for (int ow = 0; ow < 10; ++ow)
                        acc[ow] = fmaf(rf[ic][ow + kx], wv, acc[ow]);
                }
            }
        }
        const float bb = b2s[c];
        float hmax[5];
        #pragma unroll
        for (int j = 0; j < 5; ++j) {
            float v0 = acc[2*j] + bb;
            float v1 = acc[2*j + 1] + bb;
            hmax[j] = fmaxf(v0, v1);
        }
        float* ao = act + (size_t)img * 400;
        #pragma unroll
        for (int j = 0; j < 5; ++j) {
            float other = __shfl_xor(hmax[j], 1);
            if ((oh & 1) == 0) {
                float m = fmaxf(fmaxf(hmax[j], other), 0.0f);
                if (q) m = quant_comp_f(m);
                ao[c * 25 + (oh >> 1) * 5 + j] = m;
            }
        }
    }
}

// R4 fc kernel verbatim (known-good).
__global__ __launch_bounds__(256) void fc_fused_kernel(
    const float* __restrict__ act,
    const float* __restrict__ w1, const float* __restrict__ b1,
    const float* __restrict__ w2, const float* __restrict__ b2,
    const float* __restrict__ w3, const float* __restrict__ b3,
    const int* __restrict__ qflag,
    float* __restrict__ out, int B)
{
    __shared__ __align__(16) float a0[16][404];
    __shared__ __align__(16) float a1[16][124];
    __shared__ __align__(16) float a2[16][88];

    const int t = threadIdx.x;
    const bool q = (qflag[0] != 0);
    const int base = blockIdx.x * 16;

    for (int i = t; i < 16 * 400; i += 256) {
        const int im = i / 400, k = i % 400;
        if (base + im < B) a0[im][k] = act[(size_t)(base + im) * 400 + k];
    }
    __syncthreads();

    const int im = t & 15;
    const int grp = t >> 4;

    for (int o = grp; o < 120; o += 16) {
        const float4* wr = reinterpret_cast<const float4*>(w1 + o * 400);
        const float4* ar = reinterpret_cast<const float4*>(&a0[im][0]);
        float acc = 0.0f;
        #pragma unroll 4
        for (int kk = 0; kk < 100; ++kk) {
            const float4 av = ar[kk];
            const float4 wv = wr[kk];
            acc = fmaf(av.x, wv.x, acc);
            acc = fmaf(av.y, wv.y, acc);
            acc = fmaf(av.z, wv.z, acc);
            acc = fmaf(av.w, wv.w, acc);
        }
        float v = acc + b1[o];
        v = fmaxf(v, 0.0f);
        a1[im][o] = q ? quant_comp_f(v) : v;
    }
    __syncthreads();

    for (int o = grp; o < 84; o += 16) {
        const float4* wr = reinterpret_cast<const float4*>(w2 + o * 120);
        const float4* ar = reinterpret_cast<const float4*>(&a1[im][0]);
        float acc = 0.0f;
        #pragma unroll 4
        for (int kk = 0; kk < 30; ++kk) {
            const float4 av = ar[kk];
            const float4 wv = wr[kk];
            acc = fmaf(av.x, wv.x, acc);
            acc = fmaf(av.y, wv.y, acc);
            acc = fmaf(av.z, wv.z, acc);
            acc = fmaf(av.w, wv.w, acc);
        }
        float v = acc + b2[o];
        v = fmaxf(v, 0.0f);
        a2[im][o] = q ? quant_comp_f(v) : v;
    }
    __syncthreads();

    for (int o = grp; o < 10; o += 16) {
        const float4* wr = reinterpret_cast<const float4*>(w3 + o * 84);
        const float4* ar = reinterpret_cast<const float4*>(&a2[im][0]);
        float acc = 0.0f;
        #pragma unroll
        for (int kk = 0; kk < 21; ++kk) {
            const float4 av = ar[kk];
            const float4 wv = wr[kk];
            acc = fmaf(av.x, wv.x, acc);
            acc = fmaf(av.y, wv.y, acc);
            acc = fmaf(av.z, wv.z, acc);
            acc = fmaf(av.w, wv.w, acc);
        }
        if (base + im < B) out[(size_t)(base + im) * 10 + o] = acc + b3[o];
    }
}

extern "C" void kernel_launch(void* const* d_in, const int* in_sizes, int n_in,
                              void* d_out, int out_size, void* d_ws, size_t ws_size,
                              hipStream_t stream) {
    const float* x     = (const float*)d_in[0];
    const float* c1w   = (const float*)d_in[1];
    const float* c1b   = (const float*)d_in[2];
    const float* c2w   = (const float*)d_in[3];
    const float* c2b   = (const float*)d_in[4];
    const float* fc1w  = (const float*)d_in[5];
    const float* fc1b  = (const float*)d_in[6];
    const float* fc2w  = (const float*)d_in[7];
    const float* fc2b  = (const float*)d_in[8];
    const float* fc3w  = (const float*)d_in[9];
    const float* fc3b  = (const float*)d_in[10];
    const int*   qflag = (const int*)d_in[11];
    float* out = (float*)d_out;

    const int B = in_sizes[0] / 784;
    float* act = (float*)d_ws;  // [B,400]

    conv_fused_kernel<<<B, 192, 0, stream>>>(x, c1w, c1b, c2w, c2b, qflag, act);

    const int nblk = (B + 15) / 16;
    fc_fused_kernel<<<nblk, 256, 0, stream>>>(act, fc1w, fc1b, fc2w, fc2b,
                                              fc3w, fc3b, qflag, out, B);
}

// Round 9
// 332.538 us; speedup vs baseline: 11.1302x; 3.0377x over previous
//
#include <hip/hip_runtime.h>

#define Q_INV (1.0f / 128.0f)

__device__ __forceinline__ float quant_comp_f(float v) {
    float f = floorf(v * 128.0f);
    f = fminf(fmaxf(f, -128.0f), 127.0f);
    int qi = (int)f;
    qi |= 1;
    return (float)qi * Q_INV;
}

// One block per image, 192 threads. Compute loops are the exact R5 conv text
// (verified: absmax 1.464844e-3, 92 VGPR, no spill). Change vs R5: LDS arena
// union — pin -> rowmax1 -> {w2s | rowmax2} share one 3680-float buffer, so
// LDS drops 33.8KB -> ~22KB and blocks/CU rises 4 -> 7.
__global__ __launch_bounds__(192) void conv_fused_kernel(
    const float* __restrict__ x,
    const float* __restrict__ c1w, const float* __restrict__ c1b,
    const float* __restrict__ c2w, const float* __restrict__ c2b,
    const int* __restrict__ qflag,
    float* __restrict__ act)
{
    // arena: phase A: pin[32][36] (1152) ; phase B: rowmax1[6][28][17] (2856)
    //        phase C: w2s[2400] + rowmax2[160*8=1280] at +2400  -> 3680 total
    __shared__ __align__(16) float shpool[3680];
    __shared__ float w1s[150];
    __shared__ float b1s[6];
    __shared__ float b2s[16];
    __shared__ __align__(16) float mid[6][14][20];   // rows/cols 0..13 valid

    float (*pin)[36] = reinterpret_cast<float(*)[36]>(shpool);

    const int t = threadIdx.x;
    const int img = blockIdx.x;
    const bool q = (qflag[0] != 0);

    for (int i = t; i < 1152; i += 192) shpool[i] = 0.0f;
    if (t < 150) w1s[t] = c1w[t];
    if (t < 6) b1s[t] = c1b[t];
    if (t < 16) b2s[t] = c2b[t];
    __syncthreads();

    const float* xi = x + (size_t)img * 784;
    for (int i = t; i < 784; i += 192) {
        float v = xi[i];
        if (q) v = quant_comp_f(v);
        pin[i / 28 + 2][i % 28 + 2] = v;
    }
    __syncthreads();

    // ---- conv1: t<168, thread=(c, conv-row oh), 28 points, row in registers
    float hmax1[14];
    if (t < 168) {
        const int c = t / 28, oh = t % 28;
        float acc[28];
        #pragma unroll
        for (int j = 0; j < 28; ++j) acc[j] = 0.0f;
        #pragma unroll
        for (int ky = 0; ky < 5; ++ky) {
            float rbf[32];
            const float4* pr = reinterpret_cast<const float4*>(&pin[oh + ky][0]);
            #pragma unroll
            for (int j = 0; j < 8; ++j) {
                float4 v = pr[j];
                rbf[4*j] = v.x; rbf[4*j+1] = v.y; rbf[4*j+2] = v.z; rbf[4*j+3] = v.w;
            }
            #pragma unroll
            for (int kx = 0; kx < 5; ++kx) {
                const float wv = w1s[c * 25 + ky * 5 + kx];
                #pragma unroll
                for (int ow = 0; ow < 28; ++ow)
                    acc[ow] = fmaf(rbf[ow + kx], wv, acc[ow]);
            }
        }
        const float bb = b1s[c];
        #pragma unroll
        for (int j = 0; j < 14; ++j) {
            float v0 = acc[2*j] + bb;
            float v1 = acc[2*j + 1] + bb;
            hmax1[j] = fmaxf(v0, v1);
        }
    }
    __syncthreads();   // all pin reads done; arena becomes rowmax1[6][28][17]
    if (t < 168) {
        const int c = t / 28, oh = t % 28;
        #pragma unroll
        for (int j = 0; j < 14; ++j) shpool[(c * 28 + oh) * 17 + j] = hmax1[j];
    }
    __syncthreads();
    // vertical pool + relu + quant -> mid
    if (t < 84) {
        const int c = t / 14, ph = t % 14;
        #pragma unroll
        for (int j = 0; j < 14; ++j) {
            float m = fmaxf(shpool[(c * 28 + 2 * ph) * 17 + j],
                            shpool[(c * 28 + 2 * ph + 1) * 17 + j]);
            m = fmaxf(m, 0.0f);
            if (q) m = quant_comp_f(m);
            mid[c][ph][j] = m;
        }
    }
    __syncthreads();   // rowmax1 dead; arena head becomes w2s[2400]

    {
        const float4* src = reinterpret_cast<const float4*>(c2w);
        float4* dst = reinterpret_cast<float4*>(shpool);
        for (int i = t; i < 600; i += 192) dst[i] = src[i];
    }
    __syncthreads();

    const float* w2s = shpool;
    float* rowmax2 = shpool + 2400;

    // ---- conv2: t<160, thread=(c, conv-row oh), 10 points, 6-ch row-set in regs
    float hmax2[5];
    if (t < 160) {
        const int c = t / 10, oh = t % 10;
        float acc[10];
        #pragma unroll
        for (int j = 0; j < 10; ++j) acc[j] = 0.0f;
        #pragma unroll
        for (int ky = 0; ky < 5; ++ky) {
            float rb[6][16];
            #pragma unroll
            for (int ic = 0; ic < 6; ++ic) {
                const float4* mr = reinterpret_cast<const float4*>(&mid[ic][oh + ky][0]);
                #pragma unroll
                for (int j2 = 0; j2 < 4; ++j2) {
                    float4 v = mr[j2];
                    rb[ic][4*j2] = v.x; rb[ic][4*j2+1] = v.y;
                    rb[ic][4*j2+2] = v.z; rb[ic][4*j2+3] = v.w;
                }
            }
            #pragma unroll
            for (int kx = 0; kx < 5; ++kx) {
                #pragma unroll
                for (int ic = 0; ic < 6; ++ic) {
                    const float wv = w2s[(c * 6 + ic) * 25 + ky * 5 + kx];
                    #pragma unroll
                    for (int ow = 0; ow < 10; ++ow)
                        acc[ow] = fmaf(rb[ic][ow + kx], wv, acc[ow]);
                }
            }
        }
        const float bb = b2s[c];
        #pragma unroll
        for (int j = 0; j < 5; ++j) {
            float v0 = acc[2*j] + bb;
            float v1 = acc[2*j + 1] + bb;
            hmax2[j] = fmaxf(v0, v1);
        }
    }
    // rowmax2 region disjoint from w2s reads; write then barrier
    if (t < 160) {
        const int c = t / 10, oh = t % 10;
        #pragma unroll
        for (int j = 0; j < 5; ++j) rowmax2[(c * 10 + oh) * 8 + j] = hmax2[j];
    }
    __syncthreads();
    if (t < 80) {
        const int c = t / 5, ph = t % 5;
        float* ao = act + (size_t)img * 400;
        #pragma unroll
        for (int j = 0; j < 5; ++j) {
            float m = fmaxf(rowmax2[(c * 10 + 2 * ph) * 8 + j],
                            rowmax2[(c * 10 + 2 * ph + 1) * 8 + j]);
            m = fmaxf(m, 0.0f);
            if (q) m = quant_comp_f(m);
            ao[c * 25 + ph * 5 + j] = m;
        }
    }
}

// R4 fc kernel verbatim (known-good).
__global__ __launch_bounds__(256) void fc_fused_kernel(
    const float* __restrict__ act,
    const float* __restrict__ w1, const float* __restrict__ b1,
    const float* __restrict__ w2, const float* __restrict__ b2,
    const float* __restrict__ w3, const float* __restrict__ b3,
    const int* __restrict__ qflag,
    float* __restrict__ out, int B)
{
    __shared__ __align__(16) float a0[16][404];
    __shared__ __align__(16) float a1[16][124];
    __shared__ __align__(16) float a2[16][88];

    const int t = threadIdx.x;
    const bool q = (qflag[0] != 0);
    const int base = blockIdx.x * 16;

    for (int i = t; i < 16 * 400; i += 256) {
        const int im = i / 400, k = i % 400;
        if (base + im < B) a0[im][k] = act[(size_t)(base + im) * 400 + k];
    }
    __syncthreads();

    const int im = t & 15;
    const int grp = t >> 4;

    for (int o = grp; o < 120; o += 16) {
        const float4* wr = reinterpret_cast<const float4*>(w1 + o * 400);
        const float4* ar = reinterpret_cast<const float4*>(&a0[im][0]);
        float acc = 0.0f;
        #pragma unroll 4
        for (int kk = 0; kk < 100; ++kk) {
            const float4 av = ar[kk];
            const float4 wv = wr[kk];
            acc = fmaf(av.x, wv.x, acc);
            acc = fmaf(av.y, wv.y, acc);
            acc = fmaf(av.z, wv.z, acc);
            acc = fmaf(av.w, wv.w, acc);
        }
        float v = acc + b1[o];
        v = fmaxf(v, 0.0f);
        a1[im][o] = q ? quant_comp_f(v) : v;
    }
    __syncthreads();

    for (int o = grp; o < 84; o += 16) {
        const float4* wr = reinterpret_cast<const float4*>(w2 + o * 120);
        const float4* ar = reinterpret_cast<const float4*>(&a1[im][0]);
        float acc = 0.0f;
        #pragma unroll 4
        for (int kk = 0; kk < 30; ++kk) {
            const float4 av = ar[kk];
            const float4 wv = wr[kk];
            acc = fmaf(av.x, wv.x, acc);
            acc = fmaf(av.y, wv.y, acc);
            acc = fmaf(av.z, wv.z, acc);
            acc = fmaf(av.w, wv.w, acc);
        }
        float v = acc + b2[o];
        v = fmaxf(v, 0.0f);
        a2[im][o] = q ? quant_comp_f(v) : v;
    }
    __syncthreads();

    for (int o = grp; o < 10; o += 16) {
        const float4* wr = reinterpret_cast<const float4*>(w3 + o * 84);
        const float4* ar = reinterpret_cast<const float4*>(&a2[im][0]);
        float acc = 0.0f;
        #pragma unroll
        for (int kk = 0; kk < 21; ++kk) {
            const float4 av = ar[kk];
            const float4 wv = wr[kk];
            acc = fmaf(av.x, wv.x, acc);
            acc = fmaf(av.y, wv.y, acc);
            acc = fmaf(av.z, wv.z, acc);
            acc = fmaf(av.w, wv.w, acc);
        }
        if (base + im < B) out[(size_t)(base + im) * 10 + o] = acc + b3[o];
    }
}

extern "C" void kernel_launch(void* const* d_in, const int* in_sizes, int n_in,
                              void* d_out, int out_size, void* d_ws, size_t ws_size,
                              hipStream_t stream) {
    const float* x     = (const float*)d_in[0];
    const float* c1w   = (const float*)d_in[1];
    const float* c1b   = (const float*)d_in[2];
    const float* c2w   = (const float*)d_in[3];
    const float* c2b   = (const float*)d_in[4];
    const float* fc1w  = (const float*)d_in[5];
    const float* fc1b  = (const float*)d_in[6];
    const float* fc2w  = (const float*)d_in[7];
    const float* fc2b  = (const float*)d_in[8];
    const float* fc3w  = (const float*)d_in[9];
    const float* fc3b  = (const float*)d_in[10];
    const int*   qflag = (const int*)d_in[11];
    float* out = (float*)d_out;

    const int B = in_sizes[0] / 784;
    float* act = (float*)d_ws;  // [B,400]

    conv_fused_kernel<<<B, 192, 0, stream>>>(x, c1w, c1b, c2w, c2b, qflag, act);

    const int nblk = (B + 15) / 16;
    fc_fused_kernel<<<nblk, 256, 0, stream>>>(act, fc1w, fc1b, fc2w, fc2b,
                                              fc3w, fc3b, qflag, out, B);
}

// Round 10
// 324.261 us; speedup vs baseline: 11.4143x; 1.0255x over previous
//
#include <hip/hip_runtime.h>

#define Q_INV (1.0f / 128.0f)

__device__ __forceinline__ float quant_comp_f(float v) {
    float f = floorf(v * 128.0f);
    f = fminf(fmaxf(f, -128.0f), 127.0f);
    int qi = (int)f;
    qi |= 1;
    return (float)qi * Q_INV;
}

// R9 conv kernel VERBATIM (verified: 260 µs, VALUBusy 85%, absmax 1.464844e-3).
__global__ __launch_bounds__(192) void conv_fused_kernel(
    const float* __restrict__ x,
    const float* __restrict__ c1w, const float* __restrict__ c1b,
    const float* __restrict__ c2w, const float* __restrict__ c2b,
    const int* __restrict__ qflag,
    float* __restrict__ act)
{
    // arena: phase A: pin[32][36] (1152) ; phase B: rowmax1[6][28][17] (2856)
    //        phase C: w2s[2400] + rowmax2[160*8=1280] at +2400  -> 3680 total
    __shared__ __align__(16) float shpool[3680];
    __shared__ float w1s[150];
    __shared__ float b1s[6];
    __shared__ float b2s[16];
    __shared__ __align__(16) float mid[6][14][20];   // rows/cols 0..13 valid

    float (*pin)[36] = reinterpret_cast<float(*)[36]>(shpool);

    const int t = threadIdx.x;
    const int img = blockIdx.x;
    const bool q = (qflag[0] != 0);

    for (int i = t; i < 1152; i += 192) shpool[i] = 0.0f;
    if (t < 150) w1s[t] = c1w[t];
    if (t < 6) b1s[t] = c1b[t];
    if (t < 16) b2s[t] = c2b[t];
    __syncthreads();

    const float* xi = x + (size_t)img * 784;
    for (int i = t; i < 784; i += 192) {
        float v = xi[i];
        if (q) v = quant_comp_f(v);
        pin[i / 28 + 2][i % 28 + 2] = v;
    }
    __syncthreads();

    // ---- conv1: t<168, thread=(c, conv-row oh), 28 points, row in registers
    float hmax1[14];
    if (t < 168) {
        const int c = t / 28, oh = t % 28;
        float acc[28];
        #pragma unroll
        for (int j = 0; j < 28; ++j) acc[j] = 0.0f;
        #pragma unroll
        for (int ky = 0; ky < 5; ++ky) {
            float rbf[32];
            const float4* pr = reinterpret_cast<const float4*>(&pin[oh + ky][0]);
            #pragma unroll
            for (int j = 0; j < 8; ++j) {
                float4 v = pr[j];
                rbf[4*j] = v.x; rbf[4*j+1] = v.y; rbf[4*j+2] = v.z; rbf[4*j+3] = v.w;
            }
            #pragma unroll
            for (int kx = 0; kx < 5; ++kx) {
                const float wv = w1s[c * 25 + ky * 5 + kx];
                #pragma unroll
                for (int ow = 0; ow < 28; ++ow)
                    acc[ow] = fmaf(rbf[ow + kx], wv, acc[ow]);
            }
        }
        const float bb = b1s[c];
        #pragma unroll
        for (int j = 0; j < 14; ++j) {
            float v0 = acc[2*j] + bb;
            float v1 = acc[2*j + 1] + bb;
            hmax1[j] = fmaxf(v0, v1);
        }
    }
    __syncthreads();   // all pin reads done; arena becomes rowmax1[6][28][17]
    if (t < 168) {
        const int c = t / 28, oh = t % 28;
        #pragma unroll
        for (int j = 0; j < 14; ++j) shpool[(c * 28 + oh) * 17 + j] = hmax1[j];
    }
    __syncthreads();
    // vertical pool + relu + quant -> mid
    if (t < 84) {
        const int c = t / 14, ph = t % 14;
        #pragma unroll
        for (int j = 0; j < 14; ++j) {
            float m = fmaxf(shpool[(c * 28 + 2 * ph) * 17 + j],
                            shpool[(c * 28 + 2 * ph + 1) * 17 + j]);
            m = fmaxf(m, 0.0f);
            if (q) m = quant_comp_f(m);
            mid[c][ph][j] = m;
        }
    }
    __syncthreads();   // rowmax1 dead; arena head becomes w2s[2400]

    {
        const float4* src = reinterpret_cast<const float4*>(c2w);
        float4* dst = reinterpret_cast<float4*>(shpool);
        for (int i = t; i < 600; i += 192) dst[i] = src[i];
    }
    __syncthreads();

    const float* w2s = shpool;
    float* rowmax2 = shpool + 2400;

    // ---- conv2: t<160, thread=(c, conv-row oh), 10 points, 6-ch row-set in regs
    float hmax2[5];
    if (t < 160) {
        const int c = t / 10, oh = t % 10;
        float acc[10];
        #pragma unroll
        for (int j = 0; j < 10; ++j) acc[j] = 0.0f;
        #pragma unroll
        for (int ky = 0; ky < 5; ++ky) {
            float rb[6][16];
            #pragma unroll
            for (int ic = 0; ic < 6; ++ic) {
                const float4* mr = reinterpret_cast<const float4*>(&mid[ic][oh + ky][0]);
                #pragma unroll
                for (int j2 = 0; j2 < 4; ++j2) {
                    float4 v = mr[j2];
                    rb[ic][4*j2] = v.x; rb[ic][4*j2+1] = v.y;
                    rb[ic][4*j2+2] = v.z; rb[ic][4*j2+3] = v.w;
                }
            }
            #pragma unroll
            for (int kx = 0; kx < 5; ++kx) {
                #pragma unroll
                for (int ic = 0; ic < 6; ++ic) {
                    const float wv = w2s[(c * 6 + ic) * 25 + ky * 5 + kx];
                    #pragma unroll
                    for (int ow = 0; ow < 10; ++ow)
                        acc[ow] = fmaf(rb[ic][ow + kx], wv, acc[ow]);
                }
            }
        }
        const float bb = b2s[c];
        #pragma unroll
        for (int j = 0; j < 5; ++j) {
            float v0 = acc[2*j] + bb;
            float v1 = acc[2*j + 1] + bb;
            hmax2[j] = fmaxf(v0, v1);
        }
    }
    // rowmax2 region disjoint from w2s reads; write then barrier
    if (t < 160) {
        const int c = t / 10, oh = t % 10;
        #pragma unroll
        for (int j = 0; j < 5; ++j) rowmax2[(c * 10 + oh) * 8 + j] = hmax2[j];
    }
    __syncthreads();
    if (t < 80) {
        const int c = t / 5, ph = t % 5;
        float* ao = act + (size_t)img * 400;
        #pragma unroll
        for (int j = 0; j < 5; ++j) {
            float m = fmaxf(rowmax2[(c * 10 + 2 * ph) * 8 + j],
                            rowmax2[(c * 10 + 2 * ph + 1) * 8 + j]);
            m = fmaxf(m, 0.0f);
            if (q) m = quant_comp_f(m);
            ao[c * 25 + ph * 5 + j] = m;
        }
    }
}

// New fc: LDS-staged weight tiles (k-chunks of 40) + chunk-staged activations
// + dual-acc ILP. Per-output chain bit-identical to R4/R9: single fmaf chain,
// k ascending 0..K-1, bias as separate rounded add, relu, quant.
__global__ __launch_bounds__(256) void fc_fused_kernel(
    const float* __restrict__ act,
    const float* __restrict__ w1, const float* __restrict__ b1,
    const float* __restrict__ w2, const float* __restrict__ b2,
    const float* __restrict__ w3, const float* __restrict__ b3,
    const int* __restrict__ qflag,
    float* __restrict__ out, int B)
{
    __shared__ __align__(16) float wt[120][44];    // 21.1 KB weight tile
    __shared__ __align__(16) float a0c[16][44];    // 2.8 KB act chunk
    __shared__ __align__(16) float a1[16][124];
    __shared__ __align__(16) float a2[16][88];

    const int t = threadIdx.x;
    const bool q = (qflag[0] != 0);
    const int base = blockIdx.x * 16;
    const int im = t & 15;
    const int grp = t >> 4;

    // ---- fc1: 120 outs, k=400 in 10 chunks of 40 ----
    float acc[8];
    #pragma unroll
    for (int j = 0; j < 8; ++j) acc[j] = 0.0f;

    for (int ch = 0; ch < 10; ++ch) {
        __syncthreads();   // wt/a0c free of previous readers
        for (int i = t; i < 1200; i += 256) {
            const int o = i / 10, s = i % 10;
            *reinterpret_cast<float4*>(&wt[o][s * 4]) =
                *reinterpret_cast<const float4*>(w1 + o * 400 + ch * 40 + s * 4);
        }
        for (int i = t; i < 640; i += 256) {
            const int imm = i / 40, k = i % 40;
            if (base + imm < B)
                a0c[imm][k] = act[(size_t)(base + imm) * 400 + ch * 40 + k];
        }
        __syncthreads();
        #pragma unroll
        for (int r = 0; r < 4; ++r) {
            const int o0 = r * 32 + 2 * grp;
            if (o0 < 120) {
                float s0 = acc[2*r], s1 = acc[2*r+1];
                #pragma unroll
                for (int kk = 0; kk < 10; ++kk) {
                    const float4 av = *reinterpret_cast<const float4*>(&a0c[im][kk*4]);
                    const float4 wa = *reinterpret_cast<const float4*>(&wt[o0][kk*4]);
                    const float4 wb = *reinterpret_cast<const float4*>(&wt[o0+1][kk*4]);
                    s0 = fmaf(av.x, wa.x, s0); s1 = fmaf(av.x, wb.x, s1);
                    s0 = fmaf(av.y, wa.y, s0); s1 = fmaf(av.y, wb.y, s1);
                    s0 = fmaf(av.z, wa.z, s0); s1 = fmaf(av.z, wb.z, s1);
                    s0 = fmaf(av.w, wa.w, s0); s1 = fmaf(av.w, wb.w, s1);
                }
                acc[2*r] = s0; acc[2*r+1] = s1;
            }
        }
    }
    #pragma unroll
    for (int r = 0; r < 4; ++r) {
        const int o0 = r * 32 + 2 * grp;
        if (o0 < 120) {
            float v0 = acc[2*r] + b1[o0];          // separate rounded add
            float v1 = acc[2*r+1] + b1[o0+1];
            v0 = fmaxf(v0, 0.0f); v1 = fmaxf(v1, 0.0f);
            a1[im][o0]   = q ? quant_comp_f(v0) : v0;
            a1[im][o0+1] = q ? quant_comp_f(v1) : v1;
        }
    }

    // ---- fc2: 84 outs, k=120 in 3 chunks of 40 (acts read from a1 LDS) ----
    float bcc[6];
    #pragma unroll
    for (int j = 0; j < 6; ++j) bcc[j] = 0.0f;

    for (int ch = 0; ch < 3; ++ch) {
        __syncthreads();   // also orders a1 writes before reads (ch=0)
        for (int i = t; i < 840; i += 256) {
            const int o = i / 10, s = i % 10;
            *reinterpret_cast<float4*>(&wt[o][s * 4]) =
                *reinterpret_cast<const float4*>(w2 + o * 120 + ch * 40 + s * 4);
        }
        __syncthreads();
        #pragma unroll
        for (int r = 0; r < 3; ++r) {
            const int o0 = r * 32 + 2 * grp;
            if (o0 < 84) {
                float s0 = bcc[2*r], s1 = bcc[2*r+1];
                #pragma unroll
                for (int kk = 0; kk < 10; ++kk) {
                    const float4 av = *reinterpret_cast<const float4*>(&a1[im][ch*40 + kk*4]);
                    const float4 wa = *reinterpret_cast<const float4*>(&wt[o0][kk*4]);
                    const float4 wb = *reinterpret_cast<const float4*>(&wt[o0+1][kk*4]);
                    s0 = fmaf(av.x, wa.x, s0); s1 = fmaf(av.x, wb.x, s1);
                    s0 = fmaf(av.y, wa.y, s0); s1 = fmaf(av.y, wb.y, s1);
                    s0 = fmaf(av.z, wa.z, s0); s1 = fmaf(av.z, wb.z, s1);
                    s0 = fmaf(av.w, wa.w, s0); s1 = fmaf(av.w, wb.w, s1);
                }
                bcc[2*r] = s0; bcc[2*r+1] = s1;
            }
        }
    }
    #pragma unroll
    for (int r = 0; r < 3; ++r) {
        const int o0 = r * 32 + 2 * grp;
        if (o0 < 84) {
            float v0 = bcc[2*r] + b2[o0];
            float v1 = bcc[2*r+1] + b2[o0+1];
            v0 = fmaxf(v0, 0.0f); v1 = fmaxf(v1, 0.0f);
            a2[im][o0]   = q ? quant_comp_f(v0) : v0;
            a2[im][o0+1] = q ? quant_comp_f(v1) : v1;
        }
    }

    // ---- fc3: 10 outs, k=84; w3 (840 floats) staged flat in wt ----
    __syncthreads();       // a2 writes done; wt free
    {
        float* wtf = &wt[0][0];
        for (int i = t; i < 210; i += 256)
            reinterpret_cast<float4*>(wtf)[i] =
                reinterpret_cast<const float4*>(w3)[i];
    }
    __syncthreads();
    {
        const int o0 = 2 * grp;
        if (o0 < 10) {
            const float* wtf = &wt[0][0];
            float s0 = 0.0f, s1 = 0.0f;
            #pragma unroll
            for (int kk = 0; kk < 21; ++kk) {
                const float4 av = *reinterpret_cast<const float4*>(&a2[im][kk*4]);
                const float4 wa = *reinterpret_cast<const float4*>(&wtf[o0*84 + kk*4]);
                const float4 wb = *reinterpret_cast<const float4*>(&wtf[(o0+1)*84 + kk*4]);
                s0 = fmaf(av.x, wa.x, s0); s1 = fmaf(av.x, wb.x, s1);
                s0 = fmaf(av.y, wa.y, s0); s1 = fmaf(av.y, wb.y, s1);
                s0 = fmaf(av.z, wa.z, s0); s1 = fmaf(av.z, wb.z, s1);
                s0 = fmaf(av.w, wa.w, s0); s1 = fmaf(av.w, wb.w, s1);
            }
            if (base + im < B) {
                out[(size_t)(base + im) * 10 + o0]     = s0 + b3[o0];
                out[(size_t)(base + im) * 10 + o0 + 1] = s1 + b3[o0 + 1];
            }
        }
    }
}

extern "C" void kernel_launch(void* const* d_in, const int* in_sizes, int n_in,
                              void* d_out, int out_size, void* d_ws, size_t ws_size,
                              hipStream_t stream) {
    const float* x     = (const float*)d_in[0];
    const float* c1w   = (const float*)d_in[1];
    const float* c1b   = (const float*)d_in[2];
    const float* c2w   = (const float*)d_in[3];
    const float* c2b   = (const float*)d_in[4];
    const float* fc1w  = (const float*)d_in[5];
    const float* fc1b  = (const float*)d_in[6];
    const float* fc2w  = (const float*)d_in[7];
    const float* fc2b  = (const float*)d_in[8];
    const float* fc3w  = (const float*)d_in[9];
    const float* fc3b  = (const float*)d_in[10];
    const int*   qflag = (const int*)d_in[11];
    float* out = (float*)d_out;

    const int B = in_sizes[0] / 784;
    float* act = (float*)d_ws;  // [B,400]

    conv_fused_kernel<<<B, 192, 0, stream>>>(x, c1w, c1b, c2w, c2b, qflag, act);

    const int nblk = (B + 15) / 16;
    fc_fused_kernel<<<nblk, 256, 0, stream>>>(act, fc1w, fc1b, fc2w, fc2b,
                                              fc3w, fc3b, qflag, out, B);
}

// Round 11
// 324.081 us; speedup vs baseline: 11.4207x; 1.0006x over previous
//
#include <hip/hip_runtime.h>

#define Q_INV (1.0f / 128.0f)

__device__ __forceinline__ float quant_comp_f(float v) {
    float f = floorf(v * 128.0f);
    f = fminf(fmaxf(f, -128.0f), 127.0f);
    int qi = (int)f;
    qi |= 1;
    return (float)qi * Q_INV;
}

// compile-time float4 component select (c constant after unroll -> subregister
// access, no v_mov, no scratch)
__device__ __forceinline__ float getf(const float4 v, const int c) {
    return c == 0 ? v.x : (c == 1 ? v.y : (c == 2 ? v.z : v.w));
}

// R9 conv structure verbatim; only change: register row buffers are float4
// quads accessed via getf (kills any unpack v_movs). Chains bit-identical.
__global__ __launch_bounds__(192) void conv_fused_kernel(
    const float* __restrict__ x,
    const float* __restrict__ c1w, const float* __restrict__ c1b,
    const float* __restrict__ c2w, const float* __restrict__ c2b,
    const int* __restrict__ qflag,
    float* __restrict__ act)
{
    // arena: phase A: pin[32][36] (1152) ; phase B: rowmax1[6][28][17] (2856)
    //        phase C: w2s[2400] + rowmax2[160*8=1280] at +2400  -> 3680 total
    __shared__ __align__(16) float shpool[3680];
    __shared__ float w1s[150];
    __shared__ float b1s[6];
    __shared__ float b2s[16];
    __shared__ __align__(16) float mid[6][14][20];   // rows/cols 0..13 valid

    float (*pin)[36] = reinterpret_cast<float(*)[36]>(shpool);

    const int t = threadIdx.x;
    const int img = blockIdx.x;
    const bool q = (qflag[0] != 0);

    for (int i = t; i < 1152; i += 192) shpool[i] = 0.0f;
    if (t < 150) w1s[t] = c1w[t];
    if (t < 6) b1s[t] = c1b[t];
    if (t < 16) b2s[t] = c2b[t];
    __syncthreads();

    const float* xi = x + (size_t)img * 784;
    for (int i = t; i < 784; i += 192) {
        float v = xi[i];
        if (q) v = quant_comp_f(v);
        pin[i / 28 + 2][i % 28 + 2] = v;
    }
    __syncthreads();

    // ---- conv1: t<168, thread=(c, conv-row oh), 28 points, row in float4 regs
    float hmax1[14];
    if (t < 168) {
        const int c = t / 28, oh = t % 28;
        float acc[28];
        #pragma unroll
        for (int j = 0; j < 28; ++j) acc[j] = 0.0f;
        #pragma unroll
        for (int ky = 0; ky < 5; ++ky) {
            const float4* pr = reinterpret_cast<const float4*>(&pin[oh + ky][0]);
            float4 r4[8];
            #pragma unroll
            for (int j = 0; j < 8; ++j) r4[j] = pr[j];
            #pragma unroll
            for (int kx = 0; kx < 5; ++kx) {
                const float wv = w1s[c * 25 + ky * 5 + kx];
                #pragma unroll
                for (int ow = 0; ow < 28; ++ow) {
                    const int idx = ow + kx;
                    acc[ow] = fmaf(getf(r4[idx >> 2], idx & 3), wv, acc[ow]);
                }
            }
        }
        const float bb = b1s[c];
        #pragma unroll
        for (int j = 0; j < 14; ++j) {
            float v0 = acc[2*j] + bb;
            float v1 = acc[2*j + 1] + bb;
            hmax1[j] = fmaxf(v0, v1);
        }
    }
    __syncthreads();   // all pin reads done; arena becomes rowmax1[6][28][17]
    if (t < 168) {
        const int c = t / 28, oh = t % 28;
        #pragma unroll
        for (int j = 0; j < 14; ++j) shpool[(c * 28 + oh) * 17 + j] = hmax1[j];
    }
    __syncthreads();
    // vertical pool + relu + quant -> mid
    if (t < 84) {
        const int c = t / 14, ph = t % 14;
        #pragma unroll
        for (int j = 0; j < 14; ++j) {
            float m = fmaxf(shpool[(c * 28 + 2 * ph) * 17 + j],
                            shpool[(c * 28 + 2 * ph + 1) * 17 + j]);
            m = fmaxf(m, 0.0f);
            if (q) m = quant_comp_f(m);
            mid[c][ph][j] = m;
        }
    }
    __syncthreads();   // rowmax1 dead; arena head becomes w2s[2400]

    {
        const float4* src = reinterpret_cast<const float4*>(c2w);
        float4* dst = reinterpret_cast<float4*>(shpool);
        for (int i = t; i < 600; i += 192) dst[i] = src[i];
    }
    __syncthreads();

    const float* w2s = shpool;
    float* rowmax2 = shpool + 2400;

    // ---- conv2: t<160, thread=(c, conv-row oh), 10 points, float4 row quads
    float hmax2[5];
    if (t < 160) {
        const int c = t / 10, oh = t % 10;
        float acc[10];
        #pragma unroll
        for (int j = 0; j < 10; ++j) acc[j] = 0.0f;
        #pragma unroll
        for (int ky = 0; ky < 5; ++ky) {
            float4 rb4[6][4];
            #pragma unroll
            for (int ic = 0; ic < 6; ++ic) {
                const float4* mr = reinterpret_cast<const float4*>(&mid[ic][oh + ky][0]);
                #pragma unroll
                for (int j2 = 0; j2 < 4; ++j2) rb4[ic][j2] = mr[j2];
            }
            #pragma unroll
            for (int kx = 0; kx < 5; ++kx) {
                #pragma unroll
                for (int ic = 0; ic < 6; ++ic) {
                    const float wv = w2s[(c * 6 + ic) * 25 + ky * 5 + kx];
                    #pragma unroll
                    for (int ow = 0; ow < 10; ++ow) {
                        const int idx = ow + kx;
                        acc[ow] = fmaf(getf(rb4[ic][idx >> 2], idx & 3), wv, acc[ow]);
                    }
                }
            }
        }
        const float bb = b2s[c];
        #pragma unroll
        for (int j = 0; j < 5; ++j) {
            float v0 = acc[2*j] + bb;
            float v1 = acc[2*j + 1] + bb;
            hmax2[j] = fmaxf(v0, v1);
        }
    }
    // rowmax2 region disjoint from w2s reads; write then barrier
    if (t < 160) {
        const int c = t / 10, oh = t % 10;
        #pragma unroll
        for (int j = 0; j < 5; ++j) rowmax2[(c * 10 + oh) * 8 + j] = hmax2[j];
    }
    __syncthreads();
    if (t < 80) {
        const int c = t / 5, ph = t % 5;
        float* ao = act + (size_t)img * 400;
        #pragma unroll
        for (int j = 0; j < 5; ++j) {
            float m = fmaxf(rowmax2[(c * 10 + 2 * ph) * 8 + j],
                            rowmax2[(c * 10 + 2 * ph + 1) * 8 + j]);
            m = fmaxf(m, 0.0f);
            if (q) m = quant_comp_f(m);
            ao[c * 25 + ph * 5 + j] = m;
        }
    }
}

// R10 fc kernel verbatim.
__global__ __launch_bounds__(256) void fc_fused_kernel(
    const float* __restrict__ act,
    const float* __restrict__ w1, const float* __restrict__ b1,
    const float* __restrict__ w2, const float* __restrict__ b2,
    const float* __restrict__ w3, const float* __restrict__ b3,
    const int* __restrict__ qflag,
    float* __restrict__ out, int B)
{
    __shared__ __align__(16) float wt[120][44];
    __shared__ __align__(16) float a0c[16][44];
    __shared__ __align__(16) float a1[16][124];
    __shared__ __align__(16) float a2[16][88];

    const int t = threadIdx.x;
    const bool q = (qflag[0] != 0);
    const int base = blockIdx.x * 16;
    const int im = t & 15;
    const int grp = t >> 4;

    float acc[8];
    #pragma unroll
    for (int j = 0; j < 8; ++j) acc[j] = 0.0f;

    for (int ch = 0; ch < 10; ++ch) {
        __syncthreads();
        for (int i = t; i < 1200; i += 256) {
            const int o = i / 10, s = i % 10;
            *reinterpret_cast<float4*>(&wt[o][s * 4]) =
                *reinterpret_cast<const float4*>(w1 + o * 400 + ch * 40 + s * 4);
        }
        for (int i = t; i < 640; i += 256) {
            const int imm = i / 40, k = i % 40;
            if (base + imm < B)
                a0c[imm][k] = act[(size_t)(base + imm) * 400 + ch * 40 + k];
        }
        __syncthreads();
        #pragma unroll
        for (int r = 0; r < 4; ++r) {
            const int o0 = r * 32 + 2 * grp;
            if (o0 < 120) {
                float s0 = acc[2*r], s1 = acc[2*r+1];
                #pragma unroll
                for (int kk = 0; kk < 10; ++kk) {
                    const float4 av = *reinterpret_cast<const float4*>(&a0c[im][kk*4]);
                    const float4 wa = *reinterpret_cast<const float4*>(&wt[o0][kk*4]);
                    const float4 wb = *reinterpret_cast<const float4*>(&wt[o0+1][kk*4]);
                    s0 = fmaf(av.x, wa.x, s0); s1 = fmaf(av.x, wb.x, s1);
                    s0 = fmaf(av.y, wa.y, s0); s1 = fmaf(av.y, wb.y, s1);
                    s0 = fmaf(av.z, wa.z, s0); s1 = fmaf(av.z, wb.z, s1);
                    s0 = fmaf(av.w, wa.w, s0); s1 = fmaf(av.w, wb.w, s1);
                }
                acc[2*r] = s0; acc[2*r+1] = s1;
            }
        }
    }
    #pragma unroll
    for (int r = 0; r < 4; ++r) {
        const int o0 = r * 32 + 2 * grp;
        if (o0 < 120) {
            float v0 = acc[2*r] + b1[o0];
            float v1 = acc[2*r+1] + b1[o0+1];
            v0 = fmaxf(v0, 0.0f); v1 = fmaxf(v1, 0.0f);
            a1[im][o0]   = q ? quant_comp_f(v0) : v0;
            a1[im][o0+1] = q ? quant_comp_f(v1) : v1;
        }
    }

    float bcc[6];
    #pragma unroll
    for (int j = 0; j < 6; ++j) bcc[j] = 0.0f;

    for (int ch = 0; ch < 3; ++ch) {
        __syncthreads();
        for (int i = t; i < 840; i += 256) {
            const int o = i / 10, s = i % 10;
            *reinterpret_cast<float4*>(&wt[o][s * 4]) =
                *reinterpret_cast<const float4*>(w2 + o * 120 + ch * 40 + s * 4);
        }
        __syncthreads();
        #pragma unroll
        for (int r = 0; r < 3; ++r) {
            const int o0 = r * 32 + 2 * grp;
            if (o0 < 84) {
                float s0 = bcc[2*r], s1 = bcc[2*r+1];
                #pragma unroll
                for (int kk = 0; kk < 10; ++kk) {
                    const float4 av = *reinterpret_cast<const float4*>(&a1[im][ch*40 + kk*4]);
                    const float4 wa = *reinterpret_cast<const float4*>(&wt[o0][kk*4]);
                    const float4 wb = *reinterpret_cast<const float4*>(&wt[o0+1][kk*4]);
                    s0 = fmaf(av.x, wa.x, s0); s1 = fmaf(av.x, wb.x, s1);
                    s0 = fmaf(av.y, wa.y, s0); s1 = fmaf(av.y, wb.y, s1);
                    s0 = fmaf(av.z, wa.z, s0); s1 = fmaf(av.z, wb.z, s1);
                    s0 = fmaf(av.w, wa.w, s0); s1 = fmaf(av.w, wb.w, s1);
                }
                bcc[2*r] = s0; bcc[2*r+1] = s1;
            }
        }
    }
    #pragma unroll
    for (int r = 0; r < 3; ++r) {
        const int o0 = r * 32 + 2 * grp;
        if (o0 < 84) {
            float v0 = bcc[2*r] + b2[o0];
            float v1 = bcc[2*r+1] + b2[o0+1];
            v0 = fmaxf(v0, 0.0f); v1 = fmaxf(v1, 0.0f);
            a2[im][o0]   = q ? quant_comp_f(v0) : v0;
            a2[im][o0+1] = q ? quant_comp_f(v1) : v1;
        }
    }

    __syncthreads();
    {
        float* wtf = &wt[0][0];
        for (int i = t; i < 210; i += 256)
            reinterpret_cast<float4*>(wtf)[i] =
                reinterpret_cast<const float4*>(w3)[i];
    }
    __syncthreads();
    {
        const int o0 = 2 * grp;
        if (o0 < 10) {
            const float* wtf = &wt[0][0];
            float s0 = 0.0f, s1 = 0.0f;
            #pragma unroll
            for (int kk = 0; kk < 21; ++kk) {
                const float4 av = *reinterpret_cast<const float4*>(&a2[im][kk*4]);
                const float4 wa = *reinterpret_cast<const float4*>(&wtf[o0*84 + kk*4]);
                const float4 wb = *reinterpret_cast<const float4*>(&wtf[(o0+1)*84 + kk*4]);
                s0 = fmaf(av.x, wa.x, s0); s1 = fmaf(av.x, wb.x, s1);
                s0 = fmaf(av.y, wa.y, s0); s1 = fmaf(av.y, wb.y, s1);
                s0 = fmaf(av.z, wa.z, s0); s1 = fmaf(av.z, wb.z, s1);
                s0 = fmaf(av.w, wa.w, s0); s1 = fmaf(av.w, wb.w, s1);
            }
            if (base + im < B) {
                out[(size_t)(base + im) * 10 + o0]     = s0 + b3[o0];
                out[(size_t)(base + im) * 10 + o0 + 1] = s1 + b3[o0 + 1];
            }
        }
    }
}

extern "C" void kernel_launch(void* const* d_in, const int* in_sizes, int n_in,
                              void* d_out, int out_size, void* d_ws, size_t ws_size,
                              hipStream_t stream) {
    const float* x     = (const float*)d_in[0];
    const float* c1w   = (const float*)d_in[1];
    const float* c1b   = (const float*)d_in[2];
    const float* c2w   = (const float*)d_in[3];
    const float* c2b   = (const float*)d_in[4];
    const float* fc1w  = (const float*)d_in[5];
    const float* fc1b  = (const float*)d_in[6];
    const float* fc2w  = (const float*)d_in[7];
    const float* fc2b  = (const float*)d_in[8];
    const float* fc3w  = (const float*)d_in[9];
    const float* fc3b  = (const float*)d_in[10];
    const int*   qflag = (const int*)d_in[11];
    float* out = (float*)d_out;

    const int B = in_sizes[0] / 784;
    float* act = (float*)d_ws;  // [B,400]

    conv_fused_kernel<<<B, 192, 0, stream>>>(x, c1w, c1b, c2w, c2b, qflag, act);

    const int nblk = (B + 15) / 16;
    fc_fused_kernel<<<nblk, 256, 0, stream>>>(act, fc1w, fc1b, fc2w, fc2b,
                                              fc3w, fc3b, qflag, out, B);
}

// Round 12
// 295.702 us; speedup vs baseline: 12.5167x; 1.0960x over previous
//
#include <hip/hip_runtime.h>

#define Q_INV (1.0f / 128.0f)

__device__ __forceinline__ float quant_comp_f(float v) {
    float f = floorf(v * 128.0f);
    f = fminf(fmaxf(f, -128.0f), 127.0f);
    int qi = (int)f;
    qi |= 1;
    return (float)qi * Q_INV;
}

__device__ __forceinline__ float getf(const float4 v, const int c) {
    return c == 0 ? v.x : (c == 1 ? v.y : (c == 2 ? v.z : v.w));
}

// R9/R11 conv kernel verbatim (verified: 260 µs, VALUBusy 85%, VGPR 76).
__global__ __launch_bounds__(192) void conv_fused_kernel(
    const float* __restrict__ x,
    const float* __restrict__ c1w, const float* __restrict__ c1b,
    const float* __restrict__ c2w, const float* __restrict__ c2b,
    const int* __restrict__ qflag,
    float* __restrict__ act)
{
    __shared__ __align__(16) float shpool[3680];
    __shared__ float w1s[150];
    __shared__ float b1s[6];
    __shared__ float b2s[16];
    __shared__ __align__(16) float mid[6][14][20];

    float (*pin)[36] = reinterpret_cast<float(*)[36]>(shpool);

    const int t = threadIdx.x;
    const int img = blockIdx.x;
    const bool q = (qflag[0] != 0);

    for (int i = t; i < 1152; i += 192) shpool[i] = 0.0f;
    if (t < 150) w1s[t] = c1w[t];
    if (t < 6) b1s[t] = c1b[t];
    if (t < 16) b2s[t] = c2b[t];
    __syncthreads();

    const float* xi = x + (size_t)img * 784;
    for (int i = t; i < 784; i += 192) {
        float v = xi[i];
        if (q) v = quant_comp_f(v);
        pin[i / 28 + 2][i % 28 + 2] = v;
    }
    __syncthreads();

    float hmax1[14];
    if (t < 168) {
        const int c = t / 28, oh = t % 28;
        float acc[28];
        #pragma unroll
        for (int j = 0; j < 28; ++j) acc[j] = 0.0f;
        #pragma unroll
        for (int ky = 0; ky < 5; ++ky) {
            const float4* pr = reinterpret_cast<const float4*>(&pin[oh + ky][0]);
            float4 r4[8];
            #pragma unroll
            for (int j = 0; j < 8; ++j) r4[j] = pr[j];
            #pragma unroll
            for (int kx = 0; kx < 5; ++kx) {
                const float wv = w1s[c * 25 + ky * 5 + kx];
                #pragma unroll
                for (int ow = 0; ow < 28; ++ow) {
                    const int idx = ow + kx;
                    acc[ow] = fmaf(getf(r4[idx >> 2], idx & 3), wv, acc[ow]);
                }
            }
        }
        const float bb = b1s[c];
        #pragma unroll
        for (int j = 0; j < 14; ++j) {
            float v0 = acc[2*j] + bb;
            float v1 = acc[2*j + 1] + bb;
            hmax1[j] = fmaxf(v0, v1);
        }
    }
    __syncthreads();
    if (t < 168) {
        const int c = t / 28, oh = t % 28;
        #pragma unroll
        for (int j = 0; j < 14; ++j) shpool[(c * 28 + oh) * 17 + j] = hmax1[j];
    }
    __syncthreads();
    if (t < 84) {
        const int c = t / 14, ph = t % 14;
        #pragma unroll
        for (int j = 0; j < 14; ++j) {
            float m = fmaxf(shpool[(c * 28 + 2 * ph) * 17 + j],
                            shpool[(c * 28 + 2 * ph + 1) * 17 + j]);
            m = fmaxf(m, 0.0f);
            if (q) m = quant_comp_f(m);
            mid[c][ph][j] = m;
        }
    }
    __syncthreads();

    {
        const float4* src = reinterpret_cast<const float4*>(c2w);
        float4* dst = reinterpret_cast<float4*>(shpool);
        for (int i = t; i < 600; i += 192) dst[i] = src[i];
    }
    __syncthreads();

    const float* w2s = shpool;
    float* rowmax2 = shpool + 2400;

    float hmax2[5];
    if (t < 160) {
        const int c = t / 10, oh = t % 10;
        float acc[10];
        #pragma unroll
        for (int j = 0; j < 10; ++j) acc[j] = 0.0f;
        #pragma unroll
        for (int ky = 0; ky < 5; ++ky) {
            float4 rb4[6][4];
            #pragma unroll
            for (int ic = 0; ic < 6; ++ic) {
                const float4* mr = reinterpret_cast<const float4*>(&mid[ic][oh + ky][0]);
                #pragma unroll
                for (int j2 = 0; j2 < 4; ++j2) rb4[ic][j2] = mr[j2];
            }
            #pragma unroll
            for (int kx = 0; kx < 5; ++kx) {
                #pragma unroll
                for (int ic = 0; ic < 6; ++ic) {
                    const float wv = w2s[(c * 6 + ic) * 25 + ky * 5 + kx];
                    #pragma unroll
                    for (int ow = 0; ow < 10; ++ow) {
                        const int idx = ow + kx;
                        acc[ow] = fmaf(getf(rb4[ic][idx >> 2], idx & 3), wv, acc[ow]);
                    }
                }
            }
        }
        const float bb = b2s[c];
        #pragma unroll
        for (int j = 0; j < 5; ++j) {
            float v0 = acc[2*j] + bb;
            float v1 = acc[2*j + 1] + bb;
            hmax2[j] = fmaxf(v0, v1);
        }
    }
    if (t < 160) {
        const int c = t / 10, oh = t % 10;
        #pragma unroll
        for (int j = 0; j < 5; ++j) rowmax2[(c * 10 + oh) * 8 + j] = hmax2[j];
    }
    __syncthreads();
    if (t < 80) {
        const int c = t / 5, ph = t % 5;
        float* ao = act + (size_t)img * 400;
        #pragma unroll
        for (int j = 0; j < 5; ++j) {
            float m = fmaxf(rowmax2[(c * 10 + 2 * ph) * 8 + j],
                            rowmax2[(c * 10 + 2 * ph + 1) * 8 + j]);
            m = fmaxf(m, 0.0f);
            if (q) m = quant_comp_f(m);
            ao[c * 25 + ph * 5 + j] = m;
        }
    }
}

// fc rewrite: register tile 4 outs x 2 images per thread. Per kk: 6 ds_read_b128
// feed 32 FMA (3 B/FMA, half of R10). Weight rows stored PERMUTED
// (slot = j*NOG + og, orig o = og*4 + j) so a wave's 8 og-lanes read 8
// consecutive rows -> conflict-free. Chains bit-identical: per (o,im) one fmaf
// chain, k ascending 0..K-1 across chunks, bias as separate add, relu, quant.
__global__ __launch_bounds__(256) void fc_fused_kernel(
    const float* __restrict__ act,
    const float* __restrict__ w1, const float* __restrict__ b1,
    const float* __restrict__ w2, const float* __restrict__ b2,
    const float* __restrict__ w3, const float* __restrict__ b3,
    const int* __restrict__ qflag,
    float* __restrict__ out, int B)
{
    __shared__ __align__(16) float wt[120][44];
    __shared__ __align__(16) float a0c[16][44];
    __shared__ __align__(16) float a1[16][124];
    __shared__ __align__(16) float a2[16][88];

    const int t = threadIdx.x;
    const bool q = (qflag[0] != 0);
    const int base = blockIdx.x * 16;
    const int og = t >> 3;          // fc1: 0..29 (t<240)
    const int ig = t & 7;           // image pair 0..7

    // ---- fc1: 120 outs, k=400, 10 chunks of 40 ----
    float acc[4][2];
    #pragma unroll
    for (int j = 0; j < 4; ++j) { acc[j][0] = 0.0f; acc[j][1] = 0.0f; }

    for (int ch = 0; ch < 10; ++ch) {
        __syncthreads();
        for (int i = t; i < 1200; i += 256) {
            const int slot = i / 10, s = i % 10;
            const int orig = ((slot % 30) << 2) + (slot / 30);   // o = og*4+j -> slot j*30+og
            *reinterpret_cast<float4*>(&wt[slot][s * 4]) =
                *reinterpret_cast<const float4*>(w1 + orig * 400 + ch * 40 + s * 4);
        }
        for (int i = t; i < 160; i += 256) {
            const int imm = i / 10, s = i % 10;
            if (base + imm < B)
                *reinterpret_cast<float4*>(&a0c[imm][s * 4]) =
                    *reinterpret_cast<const float4*>(act + (size_t)(base + imm) * 400 + ch * 40 + s * 4);
        }
        __syncthreads();
        if (og < 30) {
            #pragma unroll
            for (int kk = 0; kk < 10; ++kk) {
                const float4 av0 = *reinterpret_cast<const float4*>(&a0c[2*ig][kk*4]);
                const float4 av1 = *reinterpret_cast<const float4*>(&a0c[2*ig+1][kk*4]);
                const float4 w0 = *reinterpret_cast<const float4*>(&wt[og][kk*4]);
                const float4 wv1 = *reinterpret_cast<const float4*>(&wt[30+og][kk*4]);
                const float4 wv2 = *reinterpret_cast<const float4*>(&wt[60+og][kk*4]);
                const float4 wv3 = *reinterpret_cast<const float4*>(&wt[90+og][kk*4]);
                acc[0][0]=fmaf(av0.x,w0.x,acc[0][0]);  acc[0][1]=fmaf(av1.x,w0.x,acc[0][1]);
                acc[1][0]=fmaf(av0.x,wv1.x,acc[1][0]); acc[1][1]=fmaf(av1.x,wv1.x,acc[1][1]);
                acc[2][0]=fmaf(av0.x,wv2.x,acc[2][0]); acc[2][1]=fmaf(av1.x,wv2.x,acc[2][1]);
                acc[3][0]=fmaf(av0.x,wv3.x,acc[3][0]); acc[3][1]=fmaf(av1.x,wv3.x,acc[3][1]);
                acc[0][0]=fmaf(av0.y,w0.y,acc[0][0]);  acc[0][1]=fmaf(av1.y,w0.y,acc[0][1]);
                acc[1][0]=fmaf(av0.y,wv1.y,acc[1][0]); acc[1][1]=fmaf(av1.y,wv1.y,acc[1][1]);
                acc[2][0]=fmaf(av0.y,wv2.y,acc[2][0]); acc[2][1]=fmaf(av1.y,wv2.y,acc[2][1]);
                acc[3][0]=fmaf(av0.y,wv3.y,acc[3][0]); acc[3][1]=fmaf(av1.y,wv3.y,acc[3][1]);
                acc[0][0]=fmaf(av0.z,w0.z,acc[0][0]);  acc[0][1]=fmaf(av1.z,w0.z,acc[0][1]);
                acc[1][0]=fmaf(av0.z,wv1.z,acc[1][0]); acc[1][1]=fmaf(av1.z,wv1.z,acc[1][1]);
                acc[2][0]=fmaf(av0.z,wv2.z,acc[2][0]); acc[2][1]=fmaf(av1.z,wv2.z,acc[2][1]);
                acc[3][0]=fmaf(av0.z,wv3.z,acc[3][0]); acc[3][1]=fmaf(av1.z,wv3.z,acc[3][1]);
                acc[0][0]=fmaf(av0.w,w0.w,acc[0][0]);  acc[0][1]=fmaf(av1.w,w0.w,acc[0][1]);
                acc[1][0]=fmaf(av0.w,wv1.w,acc[1][0]); acc[1][1]=fmaf(av1.w,wv1.w,acc[1][1]);
                acc[2][0]=fmaf(av0.w,wv2.w,acc[2][0]); acc[2][1]=fmaf(av1.w,wv2.w,acc[2][1]);
                acc[3][0]=fmaf(av0.w,wv3.w,acc[3][0]); acc[3][1]=fmaf(av1.w,wv3.w,acc[3][1]);
            }
        }
    }
    if (og < 30) {
        #pragma unroll
        for (int j = 0; j < 4; ++j) {
            const int o = og * 4 + j;
            #pragma unroll
            for (int i = 0; i < 2; ++i) {
                float v = acc[j][i] + b1[o];
                v = fmaxf(v, 0.0f);
                a1[2*ig + i][o] = q ? quant_comp_f(v) : v;
            }
        }
    }

    // ---- fc2: 84 outs, k=120, 3 chunks of 40; og2 = 0..20 (t<168) ----
    float bcc[4][2];
    #pragma unroll
    for (int j = 0; j < 4; ++j) { bcc[j][0] = 0.0f; bcc[j][1] = 0.0f; }

    for (int ch = 0; ch < 3; ++ch) {
        __syncthreads();     // orders a1 writes (ch=0) and previous wt reads
        for (int i = t; i < 840; i += 256) {
            const int slot = i / 10, s = i % 10;
            const int orig = ((slot % 21) << 2) + (slot / 21);   // o = og*4+j -> slot j*21+og
            *reinterpret_cast<float4*>(&wt[slot][s * 4]) =
                *reinterpret_cast<const float4*>(w2 + orig * 120 + ch * 40 + s * 4);
        }
        __syncthreads();
        if (og < 21) {
            #pragma unroll
            for (int kk = 0; kk < 10; ++kk) {
                const float4 av0 = *reinterpret_cast<const float4*>(&a1[2*ig][ch*40 + kk*4]);
                const float4 av1 = *reinterpret_cast<const float4*>(&a1[2*ig+1][ch*40 + kk*4]);
                const float4 w0 = *reinterpret_cast<const float4*>(&wt[og][kk*4]);
                const float4 wv1 = *reinterpret_cast<const float4*>(&wt[21+og][kk*4]);
                const float4 wv2 = *reinterpret_cast<const float4*>(&wt[42+og][kk*4]);
                const float4 wv3 = *reinterpret_cast<const float4*>(&wt[63+og][kk*4]);
                bcc[0][0]=fmaf(av0.x,w0.x,bcc[0][0]);  bcc[0][1]=fmaf(av1.x,w0.x,bcc[0][1]);
                bcc[1][0]=fmaf(av0.x,wv1.x,bcc[1][0]); bcc[1][1]=fmaf(av1.x,wv1.x,bcc[1][1]);
                bcc[2][0]=fmaf(av0.x,wv2.x,bcc[2][0]); bcc[2][1]=fmaf(av1.x,wv2.x,bcc[2][1]);
                bcc[3][0]=fmaf(av0.x,wv3.x,bcc[3][0]); bcc[3][1]=fmaf(av1.x,wv3.x,bcc[3][1]);
                bcc[0][0]=fmaf(av0.y,w0.y,bcc[0][0]);  bcc[0][1]=fmaf(av1.y,w0.y,bcc[0][1]);
                bcc[1][0]=fmaf(av0.y,wv1.y,bcc[1][0]); bcc[1][1]=fmaf(av1.y,wv1.y,bcc[1][1]);
                bcc[2][0]=fmaf(av0.y,wv2.y,bcc[2][0]); bcc[2][1]=fmaf(av1.y,wv2.y,bcc[2][1]);
                bcc[3][0]=fmaf(av0.y,wv3.y,bcc[3][0]); bcc[3][1]=fmaf(av1.y,wv3.y,bcc[3][1]);
                bcc[0][0]=fmaf(av0.z,w0.z,bcc[0][0]);  bcc[0][1]=fmaf(av1.z,w0.z,bcc[0][1]);
                bcc[1][0]=fmaf(av0.z,wv1.z,bcc[1][0]); bcc[1][1]=fmaf(av1.z,wv1.z,bcc[1][1]);
                bcc[2][0]=fmaf(av0.z,wv2.z,bcc[2][0]); bcc[2][1]=fmaf(av1.z,wv2.z,bcc[2][1]);
                bcc[3][0]=fmaf(av0.z,wv3.z,bcc[3][0]); bcc[3][1]=fmaf(av1.z,wv3.z,bcc[3][1]);
                bcc[0][0]=fmaf(av0.w,w0.w,bcc[0][0]);  bcc[0][1]=fmaf(av1.w,w0.w,bcc[0][1]);
                bcc[1][0]=fmaf(av0.w,wv1.w,bcc[1][0]); bcc[1][1]=fmaf(av1.w,wv1.w,bcc[1][1]);
                bcc[2][0]=fmaf(av0.w,wv2.w,bcc[2][0]); bcc[2][1]=fmaf(av1.w,wv2.w,bcc[2][1]);
                bcc[3][0]=fmaf(av0.w,wv3.w,bcc[3][0]); bcc[3][1]=fmaf(av1.w,wv3.w,bcc[3][1]);
            }
        }
    }
    if (og < 21) {
        #pragma unroll
        for (int j = 0; j < 4; ++j) {
            const int o = og * 4 + j;
            #pragma unroll
            for (int i = 0; i < 2; ++i) {
                float v = bcc[j][i] + b2[o];
                v = fmaxf(v, 0.0f);
                a2[2*ig + i][o] = q ? quant_comp_f(v) : v;
            }
        }
    }

    // ---- fc3: 10 outs, k=84; w3 staged flat in wt ----
    __syncthreads();
    {
        float* wtf = &wt[0][0];
        for (int i = t; i < 210; i += 256)
            reinterpret_cast<float4*>(wtf)[i] =
                reinterpret_cast<const float4*>(w3)[i];
    }
    __syncthreads();
    {
        const int grp = t >> 4;
        const int im = t & 15;
        const int o0 = 2 * grp;
        if (o0 < 10) {
            const float* wtf = &wt[0][0];
            float s0 = 0.0f, s1 = 0.0f;
            #pragma unroll
            for (int kk = 0; kk < 21; ++kk) {
                const float4 av = *reinterpret_cast<const float4*>(&a2[im][kk*4]);
                const float4 wa = *reinterpret_cast<const float4*>(&wtf[o0*84 + kk*4]);
                const float4 wb = *reinterpret_cast<const float4*>(&wtf[(o0+1)*84 + kk*4]);
                s0 = fmaf(av.x, wa.x, s0); s1 = fmaf(av.x, wb.x, s1);
                s0 = fmaf(av.y, wa.y, s0); s1 = fmaf(av.y, wb.y, s1);
                s0 = fmaf(av.z, wa.z, s0); s1 = fmaf(av.z, wb.z, s1);
                s0 = fmaf(av.w, wa.w, s0); s1 = fmaf(av.w, wb.w, s1);
            }
            if (base + im < B) {
                out[(size_t)(base + im) * 10 + o0]     = s0 + b3[o0];
                out[(size_t)(base + im) * 10 + o0 + 1] = s1 + b3[o0 + 1];
            }
        }
    }
}

extern "C" void kernel_launch(void* const* d_in, const int* in_sizes, int n_in,
                              void* d_out, int out_size, void* d_ws, size_t ws_size,
                              hipStream_t stream) {
    const float* x     = (const float*)d_in[0];
    const float* c1w   = (const float*)d_in[1];
    const float* c1b   = (const float*)d_in[2];
    const float* c2w   = (const float*)d_in[3];
    const float* c2b   = (const float*)d_in[4];
    const float* fc1w  = (const float*)d_in[5];
    const float* fc1b  = (const float*)d_in[6];
    const float* fc2w  = (const float*)d_in[7];
    const float* fc2b  = (const float*)d_in[8];
    const float* fc3w  = (const float*)d_in[9];
    const float* fc3b  = (const float*)d_in[10];
    const int*   qflag = (const int*)d_in[11];
    float* out = (float*)d_out;

    const int B = in_sizes[0] / 784;
    float* act = (float*)d_ws;  // [B,400]

    conv_fused_kernel<<<B, 192, 0, stream>>>(x, c1w, c1b, c2w, c2b, qflag, act);

    const int nblk = (B + 15) / 16;
    fc_fused_kernel<<<nblk, 256, 0, stream>>>(act, fc1w, fc1b, fc2w, fc2b,
                                              fc3w, fc3b, qflag, out, B);
}